// Round 10
// baseline (217.538 us; speedup 1.0000x reference)
//
#include <hip/hip_runtime.h>

// ---------------------------------------------------------------------------
// SelfAttention (dual cross-attention): B=4, S=1024, HID=1024, NH=16, DH=64
//   q1,k1,v1,q2,k2,v2 = x @ W*.T + b*   (bf16 MFMA, f32 accum)
//   out5 = attn(q1,k2,v2), out3 = attn(q2,k1,v1)
// ---------------------------------------------------------------------------

typedef __attribute__((ext_vector_type(8))) short bf16x8;
typedef __attribute__((ext_vector_type(4))) short bf16x4;
typedef __attribute__((ext_vector_type(4))) float f32x4;
typedef __attribute__((ext_vector_type(16))) float f32x16;
typedef __attribute__((ext_vector_type(4))) short s16x4;

#define MFMA16(a, b, c) __builtin_amdgcn_mfma_f32_16x16x32_bf16(a, b, c, 0, 0, 0)
#define BARRIER() asm volatile("s_barrier" ::: "memory")
#define VMCNT0() asm volatile("s_waitcnt vmcnt(0)" ::: "memory")

__device__ __forceinline__ f32x16 mfma32(bf16x8 a, bf16x8 b, f32x16 c) {
#if __has_builtin(__builtin_amdgcn_mfma_f32_32x32x16_bf16)
  return __builtin_amdgcn_mfma_f32_32x32x16_bf16(a, b, c, 0, 0, 0);
#else
  asm volatile("v_mfma_f32_32x32x16_bf16 %0, %1, %2, %0"
               : "+v"(c) : "v"(a), "v"(b));
  return c;
#endif
}

__device__ __forceinline__ f32x4 mfma16k(bf16x4 a, bf16x4 b, f32x4 c) {
#if __has_builtin(__builtin_amdgcn_mfma_f32_16x16x16bf16_1k)
  return __builtin_amdgcn_mfma_f32_16x16x16bf16_1k(a, b, c, 0, 0, 0);
#elif __has_builtin(__builtin_amdgcn_mfma_f32_16x16x16_bf16)
  return __builtin_amdgcn_mfma_f32_16x16x16_bf16(a, b, c, 0, 0, 0);
#else
  asm volatile("v_mfma_f32_16x16x16_bf16 %0, %1, %2, %0"
               : "+v"(c) : "v"(a), "v"(b));
  return c;
#endif
}

__device__ __forceinline__ unsigned short f2bf(float f) {
  unsigned u = __float_as_uint(f);
  u = (u + 0x7fffu + ((u >> 16) & 1u)) >> 16;  // RNE
  return (unsigned short)u;
}

__device__ __forceinline__ unsigned cvt_pk_bf16(float lo, float hi) {
  unsigned r;
  asm("v_cvt_pk_bf16_f32 %0, %1, %2" : "=v"(r) : "v"(lo), "v"(hi));
  return r;
}

__device__ __forceinline__ void gll16(const void* g, void* l) {
  __builtin_amdgcn_global_load_lds(
      (const __attribute__((address_space(1))) unsigned int*)g,
      (__attribute__((address_space(3))) unsigned int*)l, 16, 0, 0);
}

// ---------------------------------------------------------------------------
// Kernel 1: f32 -> bf16 conversion of x (4M) and the 6 weight matrices (6x1M)
// ---------------------------------------------------------------------------
__global__ __launch_bounds__(256) void convert_k(
    const float* __restrict__ x,
    const float* __restrict__ W0, const float* __restrict__ W1,
    const float* __restrict__ W2, const float* __restrict__ W3,
    const float* __restrict__ W4, const float* __restrict__ W5,
    short* __restrict__ xbf, short* __restrict__ wbf) {
  const int tid = blockIdx.x * 256 + threadIdx.x;
  const int e = tid << 2;
  const float* src;
  short* dst;
  int off;
  if (e < (4 << 20)) {
    src = x; dst = xbf; off = e;
  } else {
    const int j = e - (4 << 20);
    const int wsel = j >> 20;
    off = j & ((1 << 20) - 1);
    src = (wsel == 0) ? W0 : (wsel == 1) ? W1 : (wsel == 2) ? W2
        : (wsel == 3) ? W3 : (wsel == 4) ? W4 : W5;
    dst = wbf + ((size_t)wsel << 20);
  }
  const float4 v = *(const float4*)(src + off);
  s16x4 o;
  o.x = (short)f2bf(v.x);
  o.y = (short)f2bf(v.y);
  o.z = (short)f2bf(v.z);
  o.w = (short)f2bf(v.w);
  *(s16x4*)(dst + off) = o;
}

// ---------------------------------------------------------------------------
// Kernel 2: projection GEMM, 256x256, BK=32, 32x32x16 MFMA, register-
// pipelined. 512 thr (8 waves 2Mx4N, wave-tile 128x64, acc 8x f32x16).
// LDS 3-buffer ring (96 KB); frag double-buffer in regs (K-step granular):
//   iter T: stage(T+2) || ds_read frags(T,ks1) || MFMA(ks0 from regs)
//           vmcnt(4) certify stage(T+1); ONE barrier; ds_read frags(T+1,ks0)
//           || MFMA(ks1). MFMA never waits on same-iter LDS.
// LDS traffic/block-K-tile: 96 KB read + 32 KB write (was 232 KB) via 32x32
// fragment economics. Chunk-XOR swizzle (4x16B chunks/row, ^row&3) on
// staging source + ds_read (rule #21). Grid 384 (16M x 24N), XCD-bijective:
// 3 n-panels/XCD (1.5 MB L2-hot).
// ---------------------------------------------------------------------------
__global__ __launch_bounds__(512, 2) void proj_gemm256(
    const short* __restrict__ Ag, const short* __restrict__ Wall,
    const float* __restrict__ bq, const float* __restrict__ bk,
    const float* __restrict__ bv, const float* __restrict__ bq2,
    const float* __restrict__ bk2, const float* __restrict__ bv2,
    short* __restrict__ qkv) {
  __shared__ __align__(16) short As[3][8192];  // 256 rows x 32 k
  __shared__ __align__(16) short Bs[3][8192];  // 256 rows x 32 k

  const int bid = blockIdx.x;             // 384
  const int xcd = bid & 7, i = bid >> 3;  // 48 per XCD
  const int nb = xcd * 3 + (i >> 4);      // 24 n-panels, 3 per XCD
  const int mb = i & 15;
  const int n0 = nb << 8, m0 = mb << 8;

  const int t = threadIdx.x, lane = t & 63, w = t >> 6;
  const int hi = lane >> 5, lo = lane & 31;
  const int wr = w >> 2, wc = w & 3;      // 2M x 4N waves; wave C = 128x64

  f32x16 acc[4][2] = {};  // [mi][nj] 32x32 tiles
  bf16x8 a0[4], b0[2], a1[4], b1[2];

  auto stage = [&](int T, int buf) {
    const int k0 = T << 5;
#pragma unroll
    for (int ld = 0; ld < 2; ++ld) {
      const int slot = (ld << 9) + t;        // 0..1023
      const int rr = slot >> 2;              // row 0..255
      const int gc = (slot & 3) ^ (rr & 3);  // inverse chunk swizzle (source)
      gll16(Ag + (size_t)(m0 + rr) * 1024 + k0 + (gc << 3),
            &As[buf][slot * 8]);
      gll16(Wall + (size_t)(n0 + rr) * 1024 + k0 + (gc << 3),
            &Bs[buf][slot * 8]);
    }
  };

#define LDFRAG(AV, BV, TB, KS)                                            \
  _Pragma("unroll") for (int mi = 0; mi < 4; ++mi) {                      \
    const int rA = wr * 128 + mi * 32 + lo;                               \
    AV[mi] = *(const bf16x8*)                                             \
        &As[TB][rA * 32 + (((((KS) << 1) + hi) ^ (rA & 3)) << 3)];        \
  }                                                                       \
  _Pragma("unroll") for (int nj = 0; nj < 2; ++nj) {                      \
    const int rB = wc * 64 + nj * 32 + lo;                                \
    BV[nj] = *(const bf16x8*)                                             \
        &Bs[TB][rB * 32 + (((((KS) << 1) + hi) ^ (rB & 3)) << 3)];        \
  }

#define MFMA_C(AV, BV)                                                    \
  __builtin_amdgcn_s_setprio(1);                                          \
  _Pragma("unroll") for (int mi = 0; mi < 4; ++mi)                        \
    _Pragma("unroll") for (int nj = 0; nj < 2; ++nj)                      \
      acc[mi][nj] = mfma32(AV[mi], BV[nj], acc[mi][nj]);                  \
  __builtin_amdgcn_s_setprio(0);

  // prologue: tiles 0,1 in flight; certify tile0 (keep tile1's 4 newest)
  stage(0, 0);
  stage(1, 1);
  asm volatile("s_waitcnt vmcnt(4)" ::: "memory");
  BARRIER();
  LDFRAG(a0, b0, 0, 0);  // frags (0, ks0)

  int bufT = 0;
  for (int T = 0; T < 32; ++T) {
    const int bufN = (bufT == 2) ? 0 : bufT + 1;  // (T+1)%3
    const int bufS = (bufN == 2) ? 0 : bufN + 1;  // (T+2)%3
    if (T < 30) stage(T + 2, bufS);
    LDFRAG(a1, b1, bufT, 1);             // frags (T, ks1) -- issue
    __builtin_amdgcn_sched_barrier(0);
    MFMA_C(a0, b0);                      // ks0 (regs from last step)
    if (T < 31) {
      if (T < 30) {
        asm volatile("s_waitcnt vmcnt(4)" ::: "memory");  // tile T+1 landed
      } else {
        VMCNT0();
      }
      BARRIER();                          // buf[T+1] readable; WAR release
      LDFRAG(a0, b0, bufN, 0);            // frags (T+1, ks0) -- issue
      __builtin_amdgcn_sched_barrier(0);
    }
    MFMA_C(a1, b1);                      // ks1 (overlaps the reads above)
    bufT = bufN;
  }

#undef LDFRAG
#undef MFMA_C

  // ---- epilogue: bias + bf16 pack into attention layouts ----
  // C/D 32x32 layout: col = lane&31, row = (r&3) + 8*(r>>2) + 4*(lane>>5)
#pragma unroll
  for (int nj = 0; nj < 2; ++nj) {
    const int nn = n0 + wc * 64 + nj * 32 + lo;
    const int p = nn >> 10, nl = nn & 1023;
    const float* bp = (p == 0) ? bq : (p == 1) ? bk : (p == 2) ? bv
                    : (p == 3) ? bq2 : (p == 4) ? bk2 : bv2;
    const float bb = bp[nl];
    const int h = nl >> 6, d = nl & 63;
    const int pt = (p == 0 || p == 3) ? 0 : (p == 1 || p == 4) ? 1 : 2;
    unsigned short* dst = (unsigned short*)qkv + ((size_t)p << 22);
#pragma unroll
    for (int mi = 0; mi < 4; ++mi) {
#pragma unroll
      for (int r = 0; r < 16; ++r) {
        const int m = m0 + wr * 128 + mi * 32 + (r & 3) + ((r >> 2) << 3) +
                      (hi << 2);
        const int b = m >> 10, s = m & 1023;
        const unsigned short val = f2bf(acc[mi][nj][r] + bb);
        size_t idx;
        if (pt == 0) {
          idx = ((size_t)(((b << 4) + h) * 1024 + s) << 6) + d;
        } else if (pt == 1) {
          const int d2 = (d & 7) | (((d >> 3) ^ (s & 7)) << 3);
          idx = ((size_t)(((b << 4) + h) * 1024 + s) << 6) + d2;
        } else {
          const int tt = s >> 6, s2 = s & 63;
          const int s3 = (s2 & 7) | (((s2 >> 3) ^ (d & 7)) << 3);
          idx = ((size_t)((((b << 4) + h) * 16 + tt) * 64 + d) << 6) + s3;
        }
        dst[idx] = val;
      }
    }
  }
}

// ---------------------------------------------------------------------------
// Kernel 3: flash attention, swapped-QK^T in-register-P form (unchanged).
// ---------------------------------------------------------------------------
__global__ __launch_bounds__(256) void attn_k(const short* __restrict__ qkv,
                                              float* __restrict__ out) {
  __shared__ __align__(16) short Ks[2][64 * 64];
  __shared__ __align__(16) short Vs[2][64 * 64];

  const int L = blockIdx.x;  // 2048 blocks
  const int xcd = L & 7, ss = L >> 3;
  const int qt = ss & 15, pg = ss >> 4;
  const int pp = xcd + (pg << 3);  // all 16 q-tiles of a head share an XCD
  const int hb = pp & 63, dir = pp >> 6;

  const short* Q = qkv + ((size_t)(dir ? 3 : 0) << 22) + ((size_t)hb << 16);
  const short* K = qkv + ((size_t)(dir ? 1 : 4) << 22) + ((size_t)hb << 16);
  const short* V = qkv + ((size_t)(dir ? 2 : 5) << 22) + ((size_t)hb << 16);
  float* O = out + ((size_t)dir << 22);

  const int t = threadIdx.x, lane = t & 63, w = t >> 6;
  const int g = lane >> 4, lr = lane & 15;

  const int qrow = (qt << 6) + (w << 4) + lr;
  bf16x8 qf[2];
  qf[0] = *(const bf16x8*)(Q + qrow * 64 + g * 8);
  qf[1] = *(const bf16x8*)(Q + qrow * 64 + 32 + g * 8);

  const bf16x4 ones4 = {0x3F80, 0x3F80, 0x3F80, 0x3F80};

  f32x4 oacc[4] = {};
  f32x4 lacc = {};
  float mrun = -3.0e38f;               // running max for q = lr (log2 units)
  const float CSC = 0.18033688f;       // (1/8) * log2(e)

  const int srow = (w << 4) + (lane >> 3);  // staging row 0..63
  const int scol = (lane & 7) << 3;

  auto stage = [&](int kt, int buf) {
#pragma unroll
    for (int i = 0; i < 2; ++i) {
      gll16(K + (size_t)((kt << 6) + srow + i * 8) * 64 + scol,
            &Ks[buf][(w << 10) + (i << 9)]);
      gll16(V + (size_t)(kt << 12) + (size_t)(srow + i * 8) * 64 + scol,
            &Vs[buf][(w << 10) + (i << 9)]);
    }
  };

  stage(0, 0);
  VMCNT0();
  BARRIER();

  int cur = 0;
  for (int kt = 0; kt < 16; ++kt) {
    if (kt < 15) stage(kt + 1, cur ^ 1);

    // ---- S^T = K Q^T (swapped): lane gets P^T[k=kn*16+g*4+r][q=lr] ----
    f32x4 sc2[4] = {};
    __builtin_amdgcn_s_setprio(1);
#pragma unroll
    for (int dk = 0; dk < 2; ++dk) {
#pragma unroll
      for (int kn = 0; kn < 4; ++kn) {
        const int krow = kn * 16 + lr;
        const bf16x8 kf = *(const bf16x8*)
            &Ks[cur][krow * 64 +
                     ((((dk << 6) + (g << 4)) ^ ((krow & 7) << 4)) >> 1)];
        sc2[kn] = MFMA16(kf, qf[dk], sc2[kn]);
      }
    }
    __builtin_amdgcn_s_setprio(0);

    // ---- softmax (per-lane scalar state, defer-max) ----
    float tm = fmaxf(fmaxf(fmaxf(sc2[0][0], sc2[0][1]),
                           fmaxf(sc2[0][2], sc2[0][3])),
                     fmaxf(fmaxf(sc2[1][0], sc2[1][1]),
                           fmaxf(sc2[1][2], sc2[1][3])));
    tm = fmaxf(tm, fmaxf(fmaxf(fmaxf(sc2[2][0], sc2[2][1]),
                               fmaxf(sc2[2][2], sc2[2][3])),
                         fmaxf(fmaxf(sc2[3][0], sc2[3][1]),
                               fmaxf(sc2[3][2], sc2[3][3]))));
    const bool ok = __all(fmaf(tm, CSC, -mrun) <= 8.0f);
    if (!ok) {
      float t2 = fmaxf(tm, __shfl_xor(tm, 16));
      t2 = fmaxf(t2, __shfl_xor(t2, 32));
      const float mnew = fmaxf(mrun, t2 * CSC);
      const float scq = exp2f(mrun - mnew);  // scale for q = lr
      mrun = mnew;
#pragma unroll
      for (int r = 0; r < 4; ++r) {
        const float sr = __shfl(scq, (g << 2) + r);  // scale for q = g*4+r
        lacc[r] *= sr;
#pragma unroll
        for (int dn = 0; dn < 4; ++dn) oacc[dn][r] *= sr;
      }
    }

    bf16x4 pa[4];
#pragma unroll
    for (int kn = 0; kn < 4; ++kn) {
      const float p0 = exp2f(fmaf(sc2[kn][0], CSC, -mrun));
      const float p1 = exp2f(fmaf(sc2[kn][1], CSC, -mrun));
      const float p2 = exp2f(fmaf(sc2[kn][2], CSC, -mrun));
      const float p3 = exp2f(fmaf(sc2[kn][3], CSC, -mrun));
      union { unsigned u[2]; bf16x4 v; } pk;
      pk.u[0] = cvt_pk_bf16(p0, p1);
      pk.u[1] = cvt_pk_bf16(p2, p3);
      pa[kn] = pk.v;
    }

    // ---- O += P V ; l += P @ ones  (K=16 MFMAs, P straight from regs) ----
    __builtin_amdgcn_s_setprio(1);
#pragma unroll
    for (int kn = 0; kn < 4; ++kn) {
      lacc = mfma16k(pa[kn], ones4, lacc);
#pragma unroll
      for (int dn = 0; dn < 4; ++dn) {
        const int vrow = dn * 16 + lr;
        const int ch = (2 * kn + (g >> 1)) ^ (vrow & 7);  // 16B-chunk swizzle
        const bf16x4 vf = *(const bf16x4*)
            &Vs[cur][vrow * 64 + ch * 8 + ((g & 1) << 2)];
        oacc[dn] = mfma16k(pa[kn], vf, oacc[dn]);
      }
    }
    __builtin_amdgcn_s_setprio(0);

    VMCNT0();
    BARRIER();
    cur ^= 1;
  }

  // ---- epilogue: out[b][q][h*64+d] = oacc / l ----
  const int b = hb >> 4, h = hb & 15;
  float rl[4];
#pragma unroll
  for (int r = 0; r < 4; ++r) rl[r] = 1.0f / lacc[r];
#pragma unroll
  for (int dn = 0; dn < 4; ++dn) {
#pragma unroll
    for (int r = 0; r < 4; ++r) {
      const int q = (qt << 6) + (w << 4) + (g << 2) + r;
      const int d = dn * 16 + lr;
      O[((size_t)(b * 1024 + q) << 10) + h * 64 + d] = oacc[dn][r] * rl[r];
    }
  }
}

// ---------------------------------------------------------------------------
extern "C" void kernel_launch(void* const* d_in, const int* in_sizes, int n_in,
                              void* d_out, int out_size, void* d_ws,
                              size_t ws_size, hipStream_t stream) {
  const float* x   = (const float*)d_in[0];
  const float* Wq  = (const float*)d_in[1];
  const float* bq  = (const float*)d_in[2];
  const float* Wk  = (const float*)d_in[3];
  const float* bk  = (const float*)d_in[4];
  const float* Wv  = (const float*)d_in[5];
  const float* bv  = (const float*)d_in[6];
  const float* Wq2 = (const float*)d_in[7];
  const float* bq2 = (const float*)d_in[8];
  const float* Wk2 = (const float*)d_in[9];
  const float* bk2 = (const float*)d_in[10];
  const float* Wv2 = (const float*)d_in[11];
  const float* bv2 = (const float*)d_in[12];

  char* ws = (char*)d_ws;
  short* xbf = (short*)ws;                      // 8 MB
  short* wbf = (short*)(ws + 8388608);          // 12 MB
  short* qkv = (short*)(ws + 20971520);         // 6 x 8 MB

  convert_k<<<10240, 256, 0, stream>>>(x, Wq, Wk, Wv, Wq2, Wk2, Wv2, xbf, wbf);
  proj_gemm256<<<384, 512, 0, stream>>>(xbf, wbf, bq, bk, bv, bq2, bk2,
                                        bv2, qkv);
  attn_k<<<2048, 256, 0, stream>>>(qkv, (float*)d_out);
}

// Round 11
// 156.824 us; speedup vs baseline: 1.3871x; 1.3871x over previous
//
#include <hip/hip_runtime.h>

// ---------------------------------------------------------------------------
// SelfAttention (dual cross-attention): B=4, S=1024, HID=1024, NH=16, DH=64
//   q1,k1,v1,q2,k2,v2 = x @ W*.T + b*   (bf16 MFMA, f32 accum)
//   out5 = attn(q1,k2,v2), out3 = attn(q2,k1,v1)
// ---------------------------------------------------------------------------

typedef __attribute__((ext_vector_type(8))) short bf16x8;
typedef __attribute__((ext_vector_type(4))) short bf16x4;
typedef __attribute__((ext_vector_type(4))) float f32x4;
typedef __attribute__((ext_vector_type(4))) short s16x4;

#define MFMA16(a, b, c) __builtin_amdgcn_mfma_f32_16x16x32_bf16(a, b, c, 0, 0, 0)
#define BARRIER() asm volatile("s_barrier" ::: "memory")
#define VMCNT0() asm volatile("s_waitcnt vmcnt(0)" ::: "memory")

__device__ __forceinline__ f32x4 mfma16k(bf16x4 a, bf16x4 b, f32x4 c) {
#if __has_builtin(__builtin_amdgcn_mfma_f32_16x16x16bf16_1k)
  return __builtin_amdgcn_mfma_f32_16x16x16bf16_1k(a, b, c, 0, 0, 0);
#elif __has_builtin(__builtin_amdgcn_mfma_f32_16x16x16_bf16)
  return __builtin_amdgcn_mfma_f32_16x16x16_bf16(a, b, c, 0, 0, 0);
#else
  asm volatile("v_mfma_f32_16x16x16_bf16 %0, %1, %2, %0"
               : "+v"(c) : "v"(a), "v"(b));
  return c;
#endif
}

__device__ __forceinline__ unsigned short f2bf(float f) {
  unsigned u = __float_as_uint(f);
  u = (u + 0x7fffu + ((u >> 16) & 1u)) >> 16;  // RNE
  return (unsigned short)u;
}

__device__ __forceinline__ unsigned cvt_pk_bf16(float lo, float hi) {
  unsigned r;
  asm("v_cvt_pk_bf16_f32 %0, %1, %2" : "=v"(r) : "v"(lo), "v"(hi));
  return r;
}

__device__ __forceinline__ void gll16(const void* g, void* l) {
  __builtin_amdgcn_global_load_lds(
      (const __attribute__((address_space(1))) unsigned int*)g,
      (__attribute__((address_space(3))) unsigned int*)l, 16, 0, 0);
}

// ---------------------------------------------------------------------------
// Kernel 1: f32 -> bf16 conversion of x (4M) and the 6 weight matrices (6x1M)
// ---------------------------------------------------------------------------
__global__ __launch_bounds__(256) void convert_k(
    const float* __restrict__ x,
    const float* __restrict__ W0, const float* __restrict__ W1,
    const float* __restrict__ W2, const float* __restrict__ W3,
    const float* __restrict__ W4, const float* __restrict__ W5,
    short* __restrict__ xbf, short* __restrict__ wbf) {
  const int tid = blockIdx.x * 256 + threadIdx.x;
  const int e = tid << 2;
  const float* src;
  short* dst;
  int off;
  if (e < (4 << 20)) {
    src = x; dst = xbf; off = e;
  } else {
    const int j = e - (4 << 20);
    const int wsel = j >> 20;
    off = j & ((1 << 20) - 1);
    src = (wsel == 0) ? W0 : (wsel == 1) ? W1 : (wsel == 2) ? W2
        : (wsel == 3) ? W3 : (wsel == 4) ? W4 : W5;
    dst = wbf + ((size_t)wsel << 20);
  }
  const float4 v = *(const float4*)(src + off);
  s16x4 o;
  o.x = (short)f2bf(v.x);
  o.y = (short)f2bf(v.y);
  o.z = (short)f2bf(v.z);
  o.w = (short)f2bf(v.w);
  *(s16x4*)(dst + off) = o;
}

// ---------------------------------------------------------------------------
// Kernel 2: projection GEMM — round-7 version verbatim (best measured:
// 86.5 us, 595 TF). 8-phase 256x192, BK=64, 512 thr (8 waves 2Mx4N,
// wave-tile 128x48), fenced barriers, dribbled stage (A-h0/A-h1/B across
// ph_a/ph_b/ph_c), vmcnt(0) certify at ph_d. Grid 512 = 2 exact rounds.
// ---------------------------------------------------------------------------
__global__ __launch_bounds__(512, 2) void proj_gemm192(
    const short* __restrict__ Ag, const short* __restrict__ Wall,
    const float* __restrict__ bq, const float* __restrict__ bk,
    const float* __restrict__ bv, const float* __restrict__ bq2,
    const float* __restrict__ bk2, const float* __restrict__ bv2,
    short* __restrict__ qkv) {
  __shared__ __align__(16) short As[2][16384];  // 256 x 64
  __shared__ __align__(16) short Bs[2][12288];  // 192 x 64

  const int bid = blockIdx.x;            // 512
  const int xcd = bid & 7, k = bid >> 3; // 64 per XCD
  const int ns = k & 3, mb = k >> 2;     // 4 n-panels/XCD (1.5MB L2-hot)
  const int nbase = (xcd * 4 + ns) * 192;
  const int m0 = mb << 8;

  const int t = threadIdx.x, lane = t & 63, w = t >> 6;
  const int g = lane >> 4, lr = lane & 15;
  const int wr = w >> 2, wc = w & 3;     // 2M x 4N waves; wave C = 128x48

  f32x4 acc[2][4][3] = {};

  // stage helpers: linear LDS dest, inverse-chunk-swizzled global source
  auto stage_ah = [&](int T, int H) {  // A half H: rows H*128..+127, 2 instr
#pragma unroll
    for (int ld = 0; ld < 2; ++ld) {
      const int slot = (H << 10) + (ld << 9) + t;
      const int rr = slot >> 3;
      const int gc = (slot & 7) ^ (rr & 7);
      gll16(Ag + (size_t)(m0 + rr) * 1024 + (T << 6) + (gc << 3),
            &As[T & 1][slot * 8]);
    }
  };
  auto stage_b = [&](int T) {  // B 192 rows, 3 instr
#pragma unroll
    for (int ld = 0; ld < 3; ++ld) {
      const int slot = (ld << 9) + t;
      const int rr = slot >> 3;
      const int gc = (slot & 7) ^ (rr & 7);
      gll16(Wall + (size_t)(nbase + rr) * 1024 + (T << 6) + (gc << 3),
            &Bs[T & 1][slot * 8]);
    }
  };

  // prologue: tile 0 -> buf0
  stage_ah(0, 0); stage_ah(0, 1); stage_b(0);
  VMCNT0();
  BARRIER();

#define LOAD_A(MH, KK, TB)                                                \
  _Pragma("unroll") for (int mi = 0; mi < 4; ++mi) {                      \
    const int rA = wr * 128 + (MH) * 64 + mi * 16 + lr;                   \
    af[mi] = *(const bf16x8*)                                             \
        &As[TB][rA * 64 + ((((KK) * 4 + g) ^ (rA & 7)) << 3)];            \
  }
#define LOAD_B(KK, TB)                                                    \
  _Pragma("unroll") for (int nj = 0; nj < 3; ++nj) {                      \
    const int rB = wc * 48 + nj * 16 + lr;                                \
    bf[nj] = *(const bf16x8*)                                             \
        &Bs[TB][rB * 64 + ((((KK) * 4 + g) ^ (rB & 7)) << 3)];            \
  }
#define MFMA_PH(MH)                                                       \
  __builtin_amdgcn_s_setprio(1);                                          \
  _Pragma("unroll") for (int mi = 0; mi < 4; ++mi)                        \
    _Pragma("unroll") for (int nj = 0; nj < 3; ++nj)                      \
      acc[MH][mi][nj] = MFMA16(af[mi], bf[nj], acc[MH][mi][nj]);          \
  __builtin_amdgcn_s_setprio(0);

  // one 4-phase group: compute buf C (tile TC), dribble tile TD (if DV)
  auto group = [&](int C, int TD, bool DV) {
    bf16x8 af[4], bf[3];
    { // ph_a (kk0, mh0): 10 ds; dribble A-half0
      LOAD_A(0, 0, C); LOAD_B(0, C);
      if (DV) stage_ah(TD, 0);
      BARRIER();
      MFMA_PH(0);
      BARRIER();
    }
    { // ph_b (kk0, mh1): 4 ds (bf reused); dribble A-half1
      LOAD_A(1, 0, C);
      if (DV) stage_ah(TD, 1);
      BARRIER();
      MFMA_PH(1);
      BARRIER();
    }
    { // ph_c (kk1, mh0): 10 ds; dribble B
      LOAD_A(0, 1, C); LOAD_B(1, C);
      if (DV) stage_b(TD);
      BARRIER();
      MFMA_PH(0);
      BARRIER();
    }
    { // ph_d (kk1, mh1): 4 ds; certify dribbled tile after MFMA
      LOAD_A(1, 1, C);
      BARRIER();
      MFMA_PH(1);
      VMCNT0();
      BARRIER();
    }
  };

  for (int j = 0; j < 8; ++j) {
    group(0, 2 * j + 1, true);
    group(1, 2 * j + 2, j < 7);
  }

#undef LOAD_A
#undef LOAD_B
#undef MFMA_PH

  // ---- epilogue: bias + bf16 pack into attention layouts (per-column p) ----
#pragma unroll
  for (int nj = 0; nj < 3; ++nj) {
    const int nn = nbase + wc * 48 + nj * 16 + lr;
    const int p = nn >> 10, nl = nn & 1023;
    const float* bp = (p == 0) ? bq : (p == 1) ? bk : (p == 2) ? bv
                    : (p == 3) ? bq2 : (p == 4) ? bk2 : bv2;
    const float bb = bp[nl];
    const int h = nl >> 6, d = nl & 63;
    const int pt = (p == 0 || p == 3) ? 0 : (p == 1 || p == 4) ? 1 : 2;
    unsigned short* dst = (unsigned short*)qkv + ((size_t)p << 22);
#pragma unroll
    for (int mh = 0; mh < 2; ++mh) {
#pragma unroll
      for (int mi = 0; mi < 4; ++mi) {
#pragma unroll
        for (int r = 0; r < 4; ++r) {
          const int m = m0 + wr * 128 + mh * 64 + mi * 16 + (g << 2) + r;
          const int b = m >> 10, s = m & 1023;
          const unsigned short val = f2bf(acc[mh][mi][nj][r] + bb);
          size_t idx;
          if (pt == 0) {
            idx = ((size_t)(((b << 4) + h) * 1024 + s) << 6) + d;
          } else if (pt == 1) {
            const int d2 = (d & 7) | (((d >> 3) ^ (s & 7)) << 3);
            idx = ((size_t)(((b << 4) + h) * 1024 + s) << 6) + d2;
          } else {
            const int tt = s >> 6, s2 = s & 63;
            const int s3 = (s2 & 7) | (((s2 >> 3) ^ (d & 7)) << 3);
            idx = ((size_t)((((b << 4) + h) * 16 + tt) * 64 + d) << 6) + s3;
          }
          dst[idx] = val;
        }
      }
    }
  }
}

// ---------------------------------------------------------------------------
// Kernel 3: flash attention, swapped-QK^T in-register-P form; Q-tile doubled
// to 128 rows (8 waves, 512 thr, 16 q-rows/wave unchanged). Halves KV
// staging traffic (each KV tile now serves 128 q-rows) and halves
// barrier/stage events per unit work. Grid 1024 = 4 blocks/CU exactly.
// ---------------------------------------------------------------------------
__global__ __launch_bounds__(512) void attn_k(const short* __restrict__ qkv,
                                              float* __restrict__ out) {
  __shared__ __align__(16) short Ks[2][64 * 64];
  __shared__ __align__(16) short Vs[2][64 * 64];

  const int L = blockIdx.x;  // 1024 blocks
  const int xcd = L & 7, ss = L >> 3;   // ss 0..127
  const int qt = ss & 7, pg = ss >> 3;  // 8 q-tiles of 128 rows
  const int pp = xcd + (pg << 3);  // all q-tiles of a head share an XCD
  const int hb = pp & 63, dir = pp >> 6;

  const short* Q = qkv + ((size_t)(dir ? 3 : 0) << 22) + ((size_t)hb << 16);
  const short* K = qkv + ((size_t)(dir ? 1 : 4) << 22) + ((size_t)hb << 16);
  const short* V = qkv + ((size_t)(dir ? 2 : 5) << 22) + ((size_t)hb << 16);
  float* O = out + ((size_t)dir << 22);

  const int t = threadIdx.x, lane = t & 63, w = t >> 6;  // w 0..7
  const int g = lane >> 4, lr = lane & 15;

  const int qrow = (qt << 7) + (w << 4) + lr;
  bf16x8 qf[2];
  qf[0] = *(const bf16x8*)(Q + qrow * 64 + g * 8);
  qf[1] = *(const bf16x8*)(Q + qrow * 64 + 32 + g * 8);

  const bf16x4 ones4 = {0x3F80, 0x3F80, 0x3F80, 0x3F80};

  f32x4 oacc[4] = {};
  f32x4 lacc = {};
  float mrun = -3.0e38f;               // running max for q = lr (log2 units)
  const float CSC = 0.18033688f;       // (1/8) * log2(e)

  const int srow = t >> 3;             // staging row 0..63 (1 gll16/thread)
  const int scol = (t & 7) << 3;

  auto stage = [&](int kt, int buf) {
    gll16(K + (size_t)((kt << 6) + srow) * 64 + scol, &Ks[buf][w << 9]);
    gll16(V + (size_t)(kt << 12) + (size_t)srow * 64 + scol, &Vs[buf][w << 9]);
  };

  stage(0, 0);
  VMCNT0();
  BARRIER();

  int cur = 0;
  for (int kt = 0; kt < 16; ++kt) {
    if (kt < 15) stage(kt + 1, cur ^ 1);

    // ---- S^T = K Q^T (swapped): lane gets P^T[k=kn*16+g*4+r][q=lr] ----
    f32x4 sc2[4] = {};
    __builtin_amdgcn_s_setprio(1);
#pragma unroll
    for (int dk = 0; dk < 2; ++dk) {
#pragma unroll
      for (int kn = 0; kn < 4; ++kn) {
        const int krow = kn * 16 + lr;
        const bf16x8 kf = *(const bf16x8*)
            &Ks[cur][krow * 64 +
                     ((((dk << 6) + (g << 4)) ^ ((krow & 7) << 4)) >> 1)];
        sc2[kn] = MFMA16(kf, qf[dk], sc2[kn]);
      }
    }
    __builtin_amdgcn_s_setprio(0);

    // ---- softmax (per-lane scalar state, defer-max) ----
    float tm = fmaxf(fmaxf(fmaxf(sc2[0][0], sc2[0][1]),
                           fmaxf(sc2[0][2], sc2[0][3])),
                     fmaxf(fmaxf(sc2[1][0], sc2[1][1]),
                           fmaxf(sc2[1][2], sc2[1][3])));
    tm = fmaxf(tm, fmaxf(fmaxf(fmaxf(sc2[2][0], sc2[2][1]),
                               fmaxf(sc2[2][2], sc2[2][3])),
                         fmaxf(fmaxf(sc2[3][0], sc2[3][1]),
                               fmaxf(sc2[3][2], sc2[3][3]))));
    const bool ok = __all(fmaf(tm, CSC, -mrun) <= 8.0f);
    if (!ok) {
      float t2 = fmaxf(tm, __shfl_xor(tm, 16));
      t2 = fmaxf(t2, __shfl_xor(t2, 32));
      const float mnew = fmaxf(mrun, t2 * CSC);
      const float scq = exp2f(mrun - mnew);  // scale for q = lr
      mrun = mnew;
#pragma unroll
      for (int r = 0; r < 4; ++r) {
        const float sr = __shfl(scq, (g << 2) + r);  // scale for q = g*4+r
        lacc[r] *= sr;
#pragma unroll
        for (int dn = 0; dn < 4; ++dn) oacc[dn][r] *= sr;
      }
    }

    bf16x4 pa[4];
#pragma unroll
    for (int kn = 0; kn < 4; ++kn) {
      const float p0 = exp2f(fmaf(sc2[kn][0], CSC, -mrun));
      const float p1 = exp2f(fmaf(sc2[kn][1], CSC, -mrun));
      const float p2 = exp2f(fmaf(sc2[kn][2], CSC, -mrun));
      const float p3 = exp2f(fmaf(sc2[kn][3], CSC, -mrun));
      union { unsigned u[2]; bf16x4 v; } pk;
      pk.u[0] = cvt_pk_bf16(p0, p1);
      pk.u[1] = cvt_pk_bf16(p2, p3);
      pa[kn] = pk.v;
    }

    // ---- O += P V ; l += P @ ones  (K=16 MFMAs, P straight from regs) ----
    __builtin_amdgcn_s_setprio(1);
#pragma unroll
    for (int kn = 0; kn < 4; ++kn) {
      lacc = mfma16k(pa[kn], ones4, lacc);
#pragma unroll
      for (int dn = 0; dn < 4; ++dn) {
        const int vrow = dn * 16 + lr;
        const int ch = (2 * kn + (g >> 1)) ^ (vrow & 7);  // 16B-chunk swizzle
        const bf16x4 vf = *(const bf16x4*)
            &Vs[cur][vrow * 64 + ch * 8 + ((g & 1) << 2)];
        oacc[dn] = mfma16k(pa[kn], vf, oacc[dn]);
      }
    }
    __builtin_amdgcn_s_setprio(0);

    VMCNT0();
    BARRIER();
    cur ^= 1;
  }

  // ---- epilogue: out[b][q][h*64+d] = oacc / l ----
  const int b = hb >> 4, h = hb & 15;
  float rl[4];
#pragma unroll
  for (int r = 0; r < 4; ++r) rl[r] = 1.0f / lacc[r];
#pragma unroll
  for (int dn = 0; dn < 4; ++dn) {
#pragma unroll
    for (int r = 0; r < 4; ++r) {
      const int q = (qt << 7) + (w << 4) + (g << 2) + r;
      const int d = dn * 16 + lr;
      O[((size_t)(b * 1024 + q) << 10) + h * 64 + d] = oacc[dn][r] * rl[r];
    }
  }
}

// ---------------------------------------------------------------------------
extern "C" void kernel_launch(void* const* d_in, const int* in_sizes, int n_in,
                              void* d_out, int out_size, void* d_ws,
                              size_t ws_size, hipStream_t stream) {
  const float* x   = (const float*)d_in[0];
  const float* Wq  = (const float*)d_in[1];
  const float* bq  = (const float*)d_in[2];
  const float* Wk  = (const float*)d_in[3];
  const float* bk  = (const float*)d_in[4];
  const float* Wv  = (const float*)d_in[5];
  const float* bv  = (const float*)d_in[6];
  const float* Wq2 = (const float*)d_in[7];
  const float* bq2 = (const float*)d_in[8];
  const float* Wk2 = (const float*)d_in[9];
  const float* bk2 = (const float*)d_in[10];
  const float* Wv2 = (const float*)d_in[11];
  const float* bv2 = (const float*)d_in[12];

  char* ws = (char*)d_ws;
  short* xbf = (short*)ws;                      // 8 MB
  short* wbf = (short*)(ws + 8388608);          // 12 MB
  short* qkv = (short*)(ws + 20971520);         // 6 x 8 MB

  convert_k<<<10240, 256, 0, stream>>>(x, Wq, Wk, Wv, Wq2, Wk2, Wv2, xbf, wbf);
  proj_gemm192<<<512, 512, 0, stream>>>(xbf, wbf, bq, bk, bv, bq2, bk2,
                                        bv2, qkv);
  attn_k<<<1024, 512, 0, stream>>>(qkv, (float*)d_out);
}

// Round 12
// 155.244 us; speedup vs baseline: 1.4013x; 1.0102x over previous
//
#include <hip/hip_runtime.h>

// ---------------------------------------------------------------------------
// SelfAttention (dual cross-attention): B=4, S=1024, HID=1024, NH=16, DH=64
//   q1,k1,v1,q2,k2,v2 = x @ W*.T + b*   (bf16 MFMA, f32 accum)
//   out5 = attn(q1,k2,v2), out3 = attn(q2,k1,v1)
// ---------------------------------------------------------------------------

typedef __attribute__((ext_vector_type(8))) short bf16x8;
typedef __attribute__((ext_vector_type(4))) short bf16x4;
typedef __attribute__((ext_vector_type(4))) float f32x4;
typedef __attribute__((ext_vector_type(4))) short s16x4;

#define MFMA16(a, b, c) __builtin_amdgcn_mfma_f32_16x16x32_bf16(a, b, c, 0, 0, 0)
#define BARRIER() asm volatile("s_barrier" ::: "memory")
#define VMCNT0() asm volatile("s_waitcnt vmcnt(0)" ::: "memory")

__device__ __forceinline__ f32x4 mfma16k(bf16x4 a, bf16x4 b, f32x4 c) {
#if __has_builtin(__builtin_amdgcn_mfma_f32_16x16x16bf16_1k)
  return __builtin_amdgcn_mfma_f32_16x16x16bf16_1k(a, b, c, 0, 0, 0);
#elif __has_builtin(__builtin_amdgcn_mfma_f32_16x16x16_bf16)
  return __builtin_amdgcn_mfma_f32_16x16x16_bf16(a, b, c, 0, 0, 0);
#else
  asm volatile("v_mfma_f32_16x16x16_bf16 %0, %1, %2, %0"
               : "+v"(c) : "v"(a), "v"(b));
  return c;
#endif
}

__device__ __forceinline__ unsigned short f2bf(float f) {
  unsigned u = __float_as_uint(f);
  u = (u + 0x7fffu + ((u >> 16) & 1u)) >> 16;  // RNE
  return (unsigned short)u;
}

__device__ __forceinline__ unsigned cvt_pk_bf16(float lo, float hi) {
  unsigned r;
  asm("v_cvt_pk_bf16_f32 %0, %1, %2" : "=v"(r) : "v"(lo), "v"(hi));
  return r;
}

__device__ __forceinline__ void gll16(const void* g, void* l) {
  __builtin_amdgcn_global_load_lds(
      (const __attribute__((address_space(1))) unsigned int*)g,
      (__attribute__((address_space(3))) unsigned int*)l, 16, 0, 0);
}

// ---------------------------------------------------------------------------
// Kernel 1: f32 -> bf16 conversion of x (4M) and the 6 weight matrices (6x1M)
// ---------------------------------------------------------------------------
__global__ __launch_bounds__(256) void convert_k(
    const float* __restrict__ x,
    const float* __restrict__ W0, const float* __restrict__ W1,
    const float* __restrict__ W2, const float* __restrict__ W3,
    const float* __restrict__ W4, const float* __restrict__ W5,
    short* __restrict__ xbf, short* __restrict__ wbf) {
  const int tid = blockIdx.x * 256 + threadIdx.x;
  const int e = tid << 2;
  const float* src;
  short* dst;
  int off;
  if (e < (4 << 20)) {
    src = x; dst = xbf; off = e;
  } else {
    const int j = e - (4 << 20);
    const int wsel = j >> 20;
    off = j & ((1 << 20) - 1);
    src = (wsel == 0) ? W0 : (wsel == 1) ? W1 : (wsel == 2) ? W2
        : (wsel == 3) ? W3 : (wsel == 4) ? W4 : W5;
    dst = wbf + ((size_t)wsel << 20);
  }
  const float4 v = *(const float4*)(src + off);
  s16x4 o;
  o.x = (short)f2bf(v.x);
  o.y = (short)f2bf(v.y);
  o.z = (short)f2bf(v.z);
  o.w = (short)f2bf(v.w);
  *(s16x4*)(dst + off) = o;
}

// ---------------------------------------------------------------------------
// Kernel 2: projection GEMM, 256x192, BK=64, 512 thr (8 waves 2Mx4N,
// wave-tile 128x48). Round-12 change vs r7: 2 phases per K-tile instead of 4
// (barrier pairs 8 -> 4 per K-tile). Phase 1 = kk0 x {mh0,mh1} (14 ds_reads,
// 48 MFMA); phase 2 = kk1 x {mh0,mh1}; dribble A-halves in ph1, B in ph2;
// vmcnt(0) certify after ph2 MFMA (same WAR epochs as r7's ledger).
// Theory: 8 waves' LDS bursts serialize -> waves reach barriers skewed;
// each barrier re-pays the skew. Halving barrier count should cut the
// 53%-both-pipes-idle share. Grid 512 = 2 exact rounds.
// ---------------------------------------------------------------------------
__global__ __launch_bounds__(512, 2) void proj_gemm192(
    const short* __restrict__ Ag, const short* __restrict__ Wall,
    const float* __restrict__ bq, const float* __restrict__ bk,
    const float* __restrict__ bv, const float* __restrict__ bq2,
    const float* __restrict__ bk2, const float* __restrict__ bv2,
    short* __restrict__ qkv) {
  __shared__ __align__(16) short As[2][16384];  // 256 x 64
  __shared__ __align__(16) short Bs[2][12288];  // 192 x 64

  const int bid = blockIdx.x;            // 512
  const int xcd = bid & 7, k = bid >> 3; // 64 per XCD
  const int ns = k & 3, mb = k >> 2;     // 4 n-panels/XCD (1.5MB L2-hot)
  const int nbase = (xcd * 4 + ns) * 192;
  const int m0 = mb << 8;

  const int t = threadIdx.x, lane = t & 63, w = t >> 6;
  const int g = lane >> 4, lr = lane & 15;
  const int wr = w >> 2, wc = w & 3;     // 2M x 4N waves; wave C = 128x48

  f32x4 acc[2][4][3] = {};

  // stage helpers: linear LDS dest, inverse-chunk-swizzled global source
  auto stage_ah = [&](int T, int H) {  // A half H: rows H*128..+127, 2 instr
#pragma unroll
    for (int ld = 0; ld < 2; ++ld) {
      const int slot = (H << 10) + (ld << 9) + t;
      const int rr = slot >> 3;
      const int gc = (slot & 7) ^ (rr & 7);
      gll16(Ag + (size_t)(m0 + rr) * 1024 + (T << 6) + (gc << 3),
            &As[T & 1][slot * 8]);
    }
  };
  auto stage_b = [&](int T) {  // B 192 rows, 3 instr
#pragma unroll
    for (int ld = 0; ld < 3; ++ld) {
      const int slot = (ld << 9) + t;
      const int rr = slot >> 3;
      const int gc = (slot & 7) ^ (rr & 7);
      gll16(Wall + (size_t)(nbase + rr) * 1024 + (T << 6) + (gc << 3),
            &Bs[T & 1][slot * 8]);
    }
  };

  // prologue: tile 0 -> buf0
  stage_ah(0, 0); stage_ah(0, 1); stage_b(0);
  VMCNT0();
  BARRIER();

#define LOAD_A(AV, MH, KK, TB)                                            \
  _Pragma("unroll") for (int mi = 0; mi < 4; ++mi) {                      \
    const int rA = wr * 128 + (MH) * 64 + mi * 16 + lr;                   \
    AV[mi] = *(const bf16x8*)                                             \
        &As[TB][rA * 64 + ((((KK) * 4 + g) ^ (rA & 7)) << 3)];            \
  }
#define LOAD_B(KK, TB)                                                    \
  _Pragma("unroll") for (int nj = 0; nj < 3; ++nj) {                      \
    const int rB = wc * 48 + nj * 16 + lr;                                \
    bf[nj] = *(const bf16x8*)                                             \
        &Bs[TB][rB * 64 + ((((KK) * 4 + g) ^ (rB & 7)) << 3)];            \
  }
#define MFMA_MH(MH, AV)                                                   \
  _Pragma("unroll") for (int mi = 0; mi < 4; ++mi)                        \
    _Pragma("unroll") for (int nj = 0; nj < 3; ++nj)                      \
      acc[MH][mi][nj] = MFMA16(AV[mi], bf[nj], acc[MH][mi][nj]);

  // one 2-phase group: compute buf C (one K-tile), dribble tile TD (if DV)
  auto group = [&](int C, int TD, bool DV) {
    bf16x8 af0[4], af1[4], bf[3];
    { // phase 1: kk0 both mh (14 ds); dribble A-h0 + A-h1 (4 gll16)
      LOAD_A(af0, 0, 0, C); LOAD_A(af1, 1, 0, C); LOAD_B(0, C);
      if (DV) { stage_ah(TD, 0); stage_ah(TD, 1); }
      BARRIER();
      __builtin_amdgcn_s_setprio(1);
      MFMA_MH(0, af0);
      MFMA_MH(1, af1);
      __builtin_amdgcn_s_setprio(0);
      BARRIER();
    }
    { // phase 2: kk1 both mh (14 ds); dribble B (3 gll16); certify after MFMA
      LOAD_A(af0, 0, 1, C); LOAD_A(af1, 1, 1, C); LOAD_B(1, C);
      if (DV) stage_b(TD);
      BARRIER();
      __builtin_amdgcn_s_setprio(1);
      MFMA_MH(0, af0);
      MFMA_MH(1, af1);
      __builtin_amdgcn_s_setprio(0);
      VMCNT0();
      BARRIER();
    }
  };

  for (int j = 0; j < 8; ++j) {
    group(0, 2 * j + 1, true);
    group(1, 2 * j + 2, j < 7);
  }

#undef LOAD_A
#undef LOAD_B
#undef MFMA_MH

  // ---- epilogue: bias + bf16 pack into attention layouts (per-column p) ----
#pragma unroll
  for (int nj = 0; nj < 3; ++nj) {
    const int nn = nbase + wc * 48 + nj * 16 + lr;
    const int p = nn >> 10, nl = nn & 1023;
    const float* bp = (p == 0) ? bq : (p == 1) ? bk : (p == 2) ? bv
                    : (p == 3) ? bq2 : (p == 4) ? bk2 : bv2;
    const float bb = bp[nl];
    const int h = nl >> 6, d = nl & 63;
    const int pt = (p == 0 || p == 3) ? 0 : (p == 1 || p == 4) ? 1 : 2;
    unsigned short* dst = (unsigned short*)qkv + ((size_t)p << 22);
#pragma unroll
    for (int mh = 0; mh < 2; ++mh) {
#pragma unroll
      for (int mi = 0; mi < 4; ++mi) {
#pragma unroll
        for (int r = 0; r < 4; ++r) {
          const int m = m0 + wr * 128 + mh * 64 + mi * 16 + (g << 2) + r;
          const int b = m >> 10, s = m & 1023;
          const unsigned short val = f2bf(acc[mh][mi][nj][r] + bb);
          size_t idx;
          if (pt == 0) {
            idx = ((size_t)(((b << 4) + h) * 1024 + s) << 6) + d;
          } else if (pt == 1) {
            const int d2 = (d & 7) | (((d >> 3) ^ (s & 7)) << 3);
            idx = ((size_t)(((b << 4) + h) * 1024 + s) << 6) + d2;
          } else {
            const int tt = s >> 6, s2 = s & 63;
            const int s3 = (s2 & 7) | (((s2 >> 3) ^ (d & 7)) << 3);
            idx = ((size_t)((((b << 4) + h) * 16 + tt) * 64 + d) << 6) + s3;
          }
          dst[idx] = val;
        }
      }
    }
  }
}

// ---------------------------------------------------------------------------
// Kernel 3: flash attention, swapped-QK^T in-register-P form; 128-row Q-tile
// (8 waves, 512 thr), grid 1024 = 4 blocks/CU (unchanged from round 11).
// ---------------------------------------------------------------------------
__global__ __launch_bounds__(512) void attn_k(const short* __restrict__ qkv,
                                              float* __restrict__ out) {
  __shared__ __align__(16) short Ks[2][64 * 64];
  __shared__ __align__(16) short Vs[2][64 * 64];

  const int L = blockIdx.x;  // 1024 blocks
  const int xcd = L & 7, ss = L >> 3;   // ss 0..127
  const int qt = ss & 7, pg = ss >> 3;  // 8 q-tiles of 128 rows
  const int pp = xcd + (pg << 3);  // all q-tiles of a head share an XCD
  const int hb = pp & 63, dir = pp >> 6;

  const short* Q = qkv + ((size_t)(dir ? 3 : 0) << 22) + ((size_t)hb << 16);
  const short* K = qkv + ((size_t)(dir ? 1 : 4) << 22) + ((size_t)hb << 16);
  const short* V = qkv + ((size_t)(dir ? 2 : 5) << 22) + ((size_t)hb << 16);
  float* O = out + ((size_t)dir << 22);

  const int t = threadIdx.x, lane = t & 63, w = t >> 6;  // w 0..7
  const int g = lane >> 4, lr = lane & 15;

  const int qrow = (qt << 7) + (w << 4) + lr;
  bf16x8 qf[2];
  qf[0] = *(const bf16x8*)(Q + qrow * 64 + g * 8);
  qf[1] = *(const bf16x8*)(Q + qrow * 64 + 32 + g * 8);

  const bf16x4 ones4 = {0x3F80, 0x3F80, 0x3F80, 0x3F80};

  f32x4 oacc[4] = {};
  f32x4 lacc = {};
  float mrun = -3.0e38f;               // running max for q = lr (log2 units)
  const float CSC = 0.18033688f;       // (1/8) * log2(e)

  const int srow = t >> 3;             // staging row 0..63 (1 gll16/thread)
  const int scol = (t & 7) << 3;

  auto stage = [&](int kt, int buf) {
    gll16(K + (size_t)((kt << 6) + srow) * 64 + scol, &Ks[buf][w << 9]);
    gll16(V + (size_t)(kt << 12) + (size_t)srow * 64 + scol, &Vs[buf][w << 9]);
  };

  stage(0, 0);
  VMCNT0();
  BARRIER();

  int cur = 0;
  for (int kt = 0; kt < 16; ++kt) {
    if (kt < 15) stage(kt + 1, cur ^ 1);

    // ---- S^T = K Q^T (swapped): lane gets P^T[k=kn*16+g*4+r][q=lr] ----
    f32x4 sc2[4] = {};
    __builtin_amdgcn_s_setprio(1);
#pragma unroll
    for (int dk = 0; dk < 2; ++dk) {
#pragma unroll
      for (int kn = 0; kn < 4; ++kn) {
        const int krow = kn * 16 + lr;
        const bf16x8 kf = *(const bf16x8*)
            &Ks[cur][krow * 64 +
                     ((((dk << 6) + (g << 4)) ^ ((krow & 7) << 4)) >> 1)];
        sc2[kn] = MFMA16(kf, qf[dk], sc2[kn]);
      }
    }
    __builtin_amdgcn_s_setprio(0);

    // ---- softmax (per-lane scalar state, defer-max) ----
    float tm = fmaxf(fmaxf(fmaxf(sc2[0][0], sc2[0][1]),
                           fmaxf(sc2[0][2], sc2[0][3])),
                     fmaxf(fmaxf(sc2[1][0], sc2[1][1]),
                           fmaxf(sc2[1][2], sc2[1][3])));
    tm = fmaxf(tm, fmaxf(fmaxf(fmaxf(sc2[2][0], sc2[2][1]),
                               fmaxf(sc2[2][2], sc2[2][3])),
                         fmaxf(fmaxf(sc2[3][0], sc2[3][1]),
                               fmaxf(sc2[3][2], sc2[3][3]))));
    const bool ok = __all(fmaf(tm, CSC, -mrun) <= 8.0f);
    if (!ok) {
      float t2 = fmaxf(tm, __shfl_xor(tm, 16));
      t2 = fmaxf(t2, __shfl_xor(t2, 32));
      const float mnew = fmaxf(mrun, t2 * CSC);
      const float scq = exp2f(mrun - mnew);  // scale for q = lr
      mrun = mnew;
#pragma unroll
      for (int r = 0; r < 4; ++r) {
        const float sr = __shfl(scq, (g << 2) + r);  // scale for q = g*4+r
        lacc[r] *= sr;
#pragma unroll
        for (int dn = 0; dn < 4; ++dn) oacc[dn][r] *= sr;
      }
    }

    bf16x4 pa[4];
#pragma unroll
    for (int kn = 0; kn < 4; ++kn) {
      const float p0 = exp2f(fmaf(sc2[kn][0], CSC, -mrun));
      const float p1 = exp2f(fmaf(sc2[kn][1], CSC, -mrun));
      const float p2 = exp2f(fmaf(sc2[kn][2], CSC, -mrun));
      const float p3 = exp2f(fmaf(sc2[kn][3], CSC, -mrun));
      union { unsigned u[2]; bf16x4 v; } pk;
      pk.u[0] = cvt_pk_bf16(p0, p1);
      pk.u[1] = cvt_pk_bf16(p2, p3);
      pa[kn] = pk.v;
    }

    // ---- O += P V ; l += P @ ones  (K=16 MFMAs, P straight from regs) ----
    __builtin_amdgcn_s_setprio(1);
#pragma unroll
    for (int kn = 0; kn < 4; ++kn) {
      lacc = mfma16k(pa[kn], ones4, lacc);
#pragma unroll
      for (int dn = 0; dn < 4; ++dn) {
        const int vrow = dn * 16 + lr;
        const int ch = (2 * kn + (g >> 1)) ^ (vrow & 7);  // 16B-chunk swizzle
        const bf16x4 vf = *(const bf16x4*)
            &Vs[cur][vrow * 64 + ch * 8 + ((g & 1) << 2)];
        oacc[dn] = mfma16k(pa[kn], vf, oacc[dn]);
      }
    }
    __builtin_amdgcn_s_setprio(0);

    VMCNT0();
    BARRIER();
    cur ^= 1;
  }

  // ---- epilogue: out[b][q][h*64+d] = oacc / l ----
  const int b = hb >> 4, h = hb & 15;
  float rl[4];
#pragma unroll
  for (int r = 0; r < 4; ++r) rl[r] = 1.0f / lacc[r];
#pragma unroll
  for (int dn = 0; dn < 4; ++dn) {
#pragma unroll
    for (int r = 0; r < 4; ++r) {
      const int q = (qt << 7) + (w << 4) + (g << 2) + r;
      const int d = dn * 16 + lr;
      O[((size_t)(b * 1024 + q) << 10) + h * 64 + d] = oacc[dn][r] * rl[r];
    }
  }
}

// ---------------------------------------------------------------------------
extern "C" void kernel_launch(void* const* d_in, const int* in_sizes, int n_in,
                              void* d_out, int out_size, void* d_ws,
                              size_t ws_size, hipStream_t stream) {
  const float* x   = (const float*)d_in[0];
  const float* Wq  = (const float*)d_in[1];
  const float* bq  = (const float*)d_in[2];
  const float* Wk  = (const float*)d_in[3];
  const float* bk  = (const float*)d_in[4];
  const float* Wv  = (const float*)d_in[5];
  const float* bv  = (const float*)d_in[6];
  const float* Wq2 = (const float*)d_in[7];
  const float* bq2 = (const float*)d_in[8];
  const float* Wk2 = (const float*)d_in[9];
  const float* bk2 = (const float*)d_in[10];
  const float* Wv2 = (const float*)d_in[11];
  const float* bv2 = (const float*)d_in[12];

  char* ws = (char*)d_ws;
  short* xbf = (short*)ws;                      // 8 MB
  short* wbf = (short*)(ws + 8388608);          // 12 MB
  short* qkv = (short*)(ws + 20971520);         // 6 x 8 MB

  convert_k<<<10240, 256, 0, stream>>>(x, Wq, Wk, Wv, Wq2, Wk2, Wv2, xbf, wbf);
  proj_gemm192<<<512, 512, 0, stream>>>(xbf, wbf, bq, bk, bv, bq2, bk2,
                                        bv2, qkv);
  attn_k<<<1024, 512, 0, stream>>>(qkv, (float*)d_out);
}